// Round 17
// baseline (194.545 us; speedup 1.0000x reference)
//
#include <hip/hip_runtime.h>

typedef _Float16 f16;
typedef __attribute__((ext_vector_type(8))) _Float16 f16x8;
typedef __attribute__((ext_vector_type(16))) float f32x16;
typedef __attribute__((ext_vector_type(4))) unsigned u32x4;

#define MM 2048
#define DD 256
#define LOG2E 1.44269504088896340736f

__device__ __forceinline__ void gload_lds16(const void* g, void* l) {
    __builtin_amdgcn_global_load_lds(
        (const __attribute__((address_space(1))) unsigned int*)g,
        (__attribute__((address_space(3))) unsigned int*)l, 16, 0, 0);
}
__device__ __forceinline__ f32x16 mfma32(f16x8 a, f16x8 b, f32x16 c) {
    return __builtin_amdgcn_mfma_f32_32x32x16_f16(a, b, c, 0, 0, 0);
}
__device__ __forceinline__ void plswap(unsigned& a, unsigned& b) {
    asm volatile("v_permlane32_swap_b32 %0, %1" : "+v"(a), "+v"(b));
}
__device__ __forceinline__ unsigned pk2(float a, float b) {
    return __builtin_bit_cast(unsigned, __builtin_amdgcn_cvt_pkrtz(a, b));
}
#define SB() __builtin_amdgcn_sched_barrier(0)
#define BAR() __builtin_amdgcn_s_barrier()

// Prep (verified R2..R16): memory f32 [2048][256] -> two fp16 copies, 16B-unit layouts.
__global__ void prep_kernel(const float* __restrict__ mem,
                            f16* __restrict__ kprep, f16* __restrict__ vtprep) {
    int t = blockIdx.x * blockDim.x + threadIdx.x;
    if (t < 65536) {
        int b = t >> 10, r = t & 1023, u = r >> 5, kk = r & 31;
        const float* src = mem + (b * 32 + kk) * DD + u * 8;
        f16 o8[8];
#pragma unroll
        for (int e = 0; e < 8; ++e) o8[e] = (f16)src[e];
        *(f16x8*)(kprep + (size_t)t * 8) = *(f16x8*)o8;
    } else {
        int t2 = t - 65536;
        int b = t2 >> 10, r = t2 & 1023, u = r >> 8, d = r & 255;
        f16 o8[8];
#pragma unroll
        for (int e = 0; e < 8; ++e) o8[e] = (f16)mem[(b * 32 + u * 8 + e) * DD + d];
        *(f16x8*)(vtprep + (size_t)t2 * 8) = *(f16x8*)o8;
    }
}

// 256 blocks x 512 threads (8 waves x 32 q-rows), 8-PHASE COUNTED-VMCNT port
// (T3+T4): per tile 4 phases {8 ds_read || stage -> raw s_barrier -> 8 MFMA},
// raw barriers (no implicit vmcnt(0) drain), ONE vmcnt(4) per tile (P3).
// K staged 2 tiles ahead (P1), VT 1 ahead (P2); loads in flight across
// barriers. K ring depth 4 (64KB), VT ring depth 2 (32KB) -> 96KB, 1 blk/CU.
__launch_bounds__(512, 2)
__global__ void attn_kernel(const float* __restrict__ q,
                            const f16* __restrict__ kprep,
                            const f16* __restrict__ vtprep,
                            float* __restrict__ out) {
    __shared__ __align__(16) f16 klds[4][8192];
    __shared__ __align__(16) f16 vtlds[2][8192];

    const int tid = threadIdx.x;
    const int w = __builtin_amdgcn_readfirstlane(tid >> 6);  // 0..7
    const int lane = tid & 63;
    const int h = lane >> 5;
    const int l31 = lane & 31;
    const int q0 = blockIdx.x * 256 + w * 32;

    // Q B-frags: qf[s] lane(h,l31) elem j = Q[q0+l31][16s+8h+j]  (col=q=l31)
    f16x8 qf[16];
#pragma unroll
    for (int s = 0; s < 16; ++s) {
        const float* src = q + (size_t)(q0 + l31) * DD + s * 16 + h * 8;
        float4 a = *(const float4*)src;
        float4 b2 = *(const float4*)(src + 4);
        f16 t8[8] = {(f16)a.x, (f16)a.y, (f16)a.z, (f16)a.w,
                     (f16)b2.x, (f16)b2.y, (f16)b2.z, (f16)b2.w};
        qf[s] = *(f16x8*)t8;
    }

    f32x16 o[8];
#pragma unroll
    for (int dt = 0; dt < 8; ++dt) o[dt] = (f32x16)(0.f);
    float lpart = 0.f, mrun = -1e30f;
    f16x8 pa0 = (f16x8)(f16)0.f, pa1 = (f16x8)(f16)0.f;  // P frags of tile t-1

#define STAGE_K(t_)                                                       \
    do {                                                                  \
        const f16* s_ = kprep + (size_t)((t_)&63) * 8192;                 \
        _Pragma("unroll")                                                 \
        for (int i_ = 0; i_ < 2; ++i_)                                    \
            gload_lds16(s_ + i_ * 4096 + w * 512 + lane * 8,              \
                        &klds[(t_) & 3][i_ * 4096 + w * 512]);            \
    } while (0)
#define STAGE_VT(t_)                                                      \
    do {                                                                  \
        const f16* s_ = vtprep + (size_t)(t_)*8192;                       \
        _Pragma("unroll")                                                 \
        for (int i_ = 0; i_ < 2; ++i_)                                    \
            gload_lds16(s_ + i_ * 4096 + w * 512 + lane * 8,              \
                        &vtlds[(t_) & 1][i_ * 4096 + w * 512]);           \
    } while (0)

#define RD_K(t_, st_) (*(const f16x8*)(&klds[(t_)&3][((2 * (st_) + h) * 32 + l31) * 8]))
#define RD_V0(t_, d_) (*(const f16x8*)(&vtlds[(t_)&1][((0 + h) * 256 + (d_)*32 + l31) * 8]))
#define RD_V1(t_, d_) (*(const f16x8*)(&vtlds[(t_)&1][((2 + h) * 256 + (d_)*32 + l31) * 8]))

// softmax (base-2, defer-max) + in-register P pack -> pa0/pa1 (R8-verified)
#define SOFTMAX_PACK(s_)                                                       \
    do {                                                                       \
        float sm_ = s_[0];                                                     \
        _Pragma("unroll") for (int r_ = 1; r_ < 16; ++r_)                      \
            sm_ = fmaxf(sm_, s_[r_]);                                          \
        sm_ *= LOG2E;                                                          \
        if (__any(sm_ > mrun + 8.0f)) {                                        \
            sm_ = fmaxf(sm_, __shfl_xor(sm_, 32));                             \
            const float mn_ = fmaxf(mrun, sm_);                                \
            const float fct_ = __builtin_amdgcn_exp2f(mrun - mn_);             \
            mrun = mn_;                                                        \
            lpart *= fct_;                                                     \
            float fr_[16];                                                     \
            _Pragma("unroll") for (int r_ = 0; r_ < 16; ++r_)                  \
                fr_[r_] = __shfl(fct_, (r_ & 3) + 8 * (r_ >> 2) + 4 * h, 32);  \
            _Pragma("unroll") for (int dt_ = 0; dt_ < 8; ++dt_)                \
                _Pragma("unroll") for (int r_ = 0; r_ < 16; ++r_)              \
                    o[dt_][r_] *= fr_[r_];                                     \
        }                                                                      \
        float p_[16], rs_ = 0.f;                                               \
        _Pragma("unroll") for (int r_ = 0; r_ < 16; ++r_) {                    \
            p_[r_] = __builtin_amdgcn_exp2f(                                   \
                __builtin_fmaf(s_[r_], LOG2E, -mrun));                         \
            rs_ += p_[r_];                                                     \
        }                                                                      \
        lpart += rs_;                                                          \
        unsigned c0_ = pk2(p_[0], p_[1]), c1_ = pk2(p_[2], p_[3]);             \
        unsigned c2_ = pk2(p_[4], p_[5]), c3_ = pk2(p_[6], p_[7]);             \
        unsigned c4_ = pk2(p_[8], p_[9]), c5_ = pk2(p_[10], p_[11]);           \
        unsigned c6_ = pk2(p_[12], p_[13]), c7_ = pk2(p_[14], p_[15]);         \
        plswap(c0_, c2_); plswap(c1_, c3_);                                    \
        plswap(c4_, c6_); plswap(c5_, c7_);                                    \
        u32x4 k0_ = {c0_, c1_, c2_, c3_}, k1_ = {c4_, c5_, c6_, c7_};          \
        pa0 = __builtin_bit_cast(f16x8, k0_);                                  \
        pa1 = __builtin_bit_cast(f16x8, k1_);                                  \
    } while (0)

    // ---- prologue: K(0), K(1) in flight (4 gload instr/thread)
    STAGE_K(0);
    STAGE_K(1);

    // ---- peeled tile 0 (QK + softmax only; no PV) ----
    {
        asm volatile("s_waitcnt vmcnt(2)" ::: "memory");  // K(0) resident
        SB(); BAR(); SB();
        f32x16 s = (f32x16)(0.f);
        // P1(0)
        {
            f16x8 a0 = RD_K(0, 0), a1 = RD_K(0, 1), a2 = RD_K(0, 2), a3 = RD_K(0, 3);
            f16x8 a4 = RD_K(0, 4), a5 = RD_K(0, 5), a6 = RD_K(0, 6), a7 = RD_K(0, 7);
            STAGE_K(2);
            SB(); BAR(); SB();
            __builtin_amdgcn_s_setprio(1);
            s = mfma32(a0, qf[0], s); s = mfma32(a1, qf[1], s);
            s = mfma32(a2, qf[2], s); s = mfma32(a3, qf[3], s);
            s = mfma32(a4, qf[4], s); s = mfma32(a5, qf[5], s);
            s = mfma32(a6, qf[6], s); s = mfma32(a7, qf[7], s);
            __builtin_amdgcn_s_setprio(0);
            BAR();
        }
        // P2(0)
        {
            f16x8 a0 = RD_K(0, 8), a1 = RD_K(0, 9), a2 = RD_K(0, 10), a3 = RD_K(0, 11);
            f16x8 a4 = RD_K(0, 12), a5 = RD_K(0, 13), a6 = RD_K(0, 14), a7 = RD_K(0, 15);
            STAGE_VT(0);
            SB(); BAR(); SB();
            __builtin_amdgcn_s_setprio(1);
            s = mfma32(a0, qf[8], s); s = mfma32(a1, qf[9], s);
            s = mfma32(a2, qf[10], s); s = mfma32(a3, qf[11], s);
            s = mfma32(a4, qf[12], s); s = mfma32(a5, qf[13], s);
            s = mfma32(a6, qf[14], s); s = mfma32(a7, qf[15], s);
            __builtin_amdgcn_s_setprio(0);
            BAR();
        }
        SOFTMAX_PACK(s);
        // tail-wait: K(1) resident before loop t=1 reads it
        asm volatile("s_waitcnt vmcnt(4)" ::: "memory");
        SB(); BAR(); SB();
    }

    // ---- main loop t = 1..63: 4 phases/tile, one vmcnt(4)/tile (P3) ----
    for (int t = 1; t < 64; ++t) {
        f32x16 s = (f32x16)(0.f);
        // P1: QK lo || stage K(t+2)
        {
            f16x8 a0 = RD_K(t, 0), a1 = RD_K(t, 1), a2 = RD_K(t, 2), a3 = RD_K(t, 3);
            f16x8 a4 = RD_K(t, 4), a5 = RD_K(t, 5), a6 = RD_K(t, 6), a7 = RD_K(t, 7);
            STAGE_K(t + 2);
            SB(); BAR(); SB();
            __builtin_amdgcn_s_setprio(1);
            s = mfma32(a0, qf[0], s); s = mfma32(a1, qf[1], s);
            s = mfma32(a2, qf[2], s); s = mfma32(a3, qf[3], s);
            s = mfma32(a4, qf[4], s); s = mfma32(a5, qf[5], s);
            s = mfma32(a6, qf[6], s); s = mfma32(a7, qf[7], s);
            __builtin_amdgcn_s_setprio(0);
            BAR();
        }
        // P2: QK hi || stage VT(t)
        {
            f16x8 a0 = RD_K(t, 8), a1 = RD_K(t, 9), a2 = RD_K(t, 10), a3 = RD_K(t, 11);
            f16x8 a4 = RD_K(t, 12), a5 = RD_K(t, 13), a6 = RD_K(t, 14), a7 = RD_K(t, 15);
            STAGE_VT(t);
            SB(); BAR(); SB();
            __builtin_amdgcn_s_setprio(1);
            s = mfma32(a0, qf[8], s); s = mfma32(a1, qf[9], s);
            s = mfma32(a2, qf[10], s); s = mfma32(a3, qf[11], s);
            s = mfma32(a4, qf[12], s); s = mfma32(a5, qf[13], s);
            s = mfma32(a6, qf[14], s); s = mfma32(a7, qf[15], s);
            __builtin_amdgcn_s_setprio(0);
            BAR();
        }
        // P3: counted drain (VT(t-1) resident; K(t+2)/VT(t) stay in flight),
        //     then PV lo on V(t-1)
        {
            asm volatile("s_waitcnt vmcnt(4)" ::: "memory");
            SB(); BAR(); SB();
            f16x8 v00 = RD_V0(t - 1, 0), v10 = RD_V1(t - 1, 0);
            f16x8 v01 = RD_V0(t - 1, 1), v11 = RD_V1(t - 1, 1);
            f16x8 v02 = RD_V0(t - 1, 2), v12 = RD_V1(t - 1, 2);
            f16x8 v03 = RD_V0(t - 1, 3), v13 = RD_V1(t - 1, 3);
            __builtin_amdgcn_s_setprio(1);
            o[0] = mfma32(pa0, v00, o[0]); o[0] = mfma32(pa1, v10, o[0]);
            o[1] = mfma32(pa0, v01, o[1]); o[1] = mfma32(pa1, v11, o[1]);
            o[2] = mfma32(pa0, v02, o[2]); o[2] = mfma32(pa1, v12, o[2]);
            o[3] = mfma32(pa0, v03, o[3]); o[3] = mfma32(pa1, v13, o[3]);
            __builtin_amdgcn_s_setprio(0);
            BAR();
        }
        // P4: PV hi on V(t-1)
        {
            f16x8 v04 = RD_V0(t - 1, 4), v14 = RD_V1(t - 1, 4);
            f16x8 v05 = RD_V0(t - 1, 5), v15 = RD_V1(t - 1, 5);
            f16x8 v06 = RD_V0(t - 1, 6), v16 = RD_V1(t - 1, 6);
            f16x8 v07 = RD_V0(t - 1, 7), v17 = RD_V1(t - 1, 7);
            SB(); BAR(); SB();
            __builtin_amdgcn_s_setprio(1);
            o[4] = mfma32(pa0, v04, o[4]); o[4] = mfma32(pa1, v14, o[4]);
            o[5] = mfma32(pa0, v05, o[5]); o[5] = mfma32(pa1, v15, o[5]);
            o[6] = mfma32(pa0, v06, o[6]); o[6] = mfma32(pa1, v16, o[6]);
            o[7] = mfma32(pa0, v07, o[7]); o[7] = mfma32(pa1, v17, o[7]);
            __builtin_amdgcn_s_setprio(0);
            BAR();
        }
        SOFTMAX_PACK(s);
    }

    // ---- epilogue: full drain (retires wrapped K stages), PV(63), store ----
    asm volatile("s_waitcnt vmcnt(0)" ::: "memory");
    SB(); BAR(); SB();
    __builtin_amdgcn_s_setprio(1);
#pragma unroll
    for (int dt = 0; dt < 8; ++dt) {
        f16x8 v0 = RD_V0(63, dt), v1 = RD_V1(63, dt);
        o[dt] = mfma32(pa0, v0, o[dt]);
        o[dt] = mfma32(pa1, v1, o[dt]);
    }
    __builtin_amdgcn_s_setprio(0);

    const float ltot = lpart + __shfl_xor(lpart, 32);
    const float inv = 1.0f / ltot;
    float invr[16];
#pragma unroll
    for (int r = 0; r < 16; ++r)
        invr[r] = __shfl(inv, (r & 3) + 8 * (r >> 2) + 4 * h, 32);
#pragma unroll
    for (int dt = 0; dt < 8; ++dt)
#pragma unroll
        for (int r = 0; r < 16; ++r) {
            const int qrow = (r & 3) + 8 * (r >> 2) + 4 * h;
            out[(size_t)(q0 + qrow) * DD + dt * 32 + l31] = o[dt][r] * invr[r];
        }
}

extern "C" void kernel_launch(void* const* d_in, const int* in_sizes, int n_in,
                              void* d_out, int out_size, void* d_ws, size_t ws_size,
                              hipStream_t stream) {
    const float* memory = (const float*)d_in[0];
    const float* query = (const float*)d_in[1];
    float* out = (float*)d_out;
    f16* kprep = (f16*)d_ws;                 // 1 MB
    f16* vtprep = kprep + (size_t)MM * DD;   // 1 MB
    prep_kernel<<<512, 256, 0, stream>>>(memory, kprep, vtprep);
    attn_kernel<<<256, 512, 0, stream>>>(query, kprep, vtprep, out);
}

// Round 18
// 150.449 us; speedup vs baseline: 1.2931x; 1.2931x over previous
//
#include <hip/hip_runtime.h>

typedef _Float16 f16;
typedef __attribute__((ext_vector_type(8))) _Float16 f16x8;
typedef __attribute__((ext_vector_type(16))) float f32x16;
typedef __attribute__((ext_vector_type(4))) unsigned u32x4;

#define MM 2048
#define DD 256
#define LOG2E 1.44269504088896340736f

__device__ __forceinline__ void gload_lds16(const void* g, void* l) {
    __builtin_amdgcn_global_load_lds(
        (const __attribute__((address_space(1))) unsigned int*)g,
        (__attribute__((address_space(3))) unsigned int*)l, 16, 0, 0);
}
__device__ __forceinline__ f32x16 mfma32(f16x8 a, f16x8 b, f32x16 c) {
    return __builtin_amdgcn_mfma_f32_32x32x16_f16(a, b, c, 0, 0, 0);
}
__device__ __forceinline__ void plswap(unsigned& a, unsigned& b) {
    asm volatile("v_permlane32_swap_b32 %0, %1" : "+v"(a), "+v"(b));
}
__device__ __forceinline__ unsigned pk2(float a, float b) {
    return __builtin_bit_cast(unsigned, __builtin_amdgcn_cvt_pkrtz(a, b));
}

// Prep (verified R2..R16): memory f32 [2048][256] -> two fp16 copies, 16B-unit layouts.
__global__ void prep_kernel(const float* __restrict__ mem,
                            f16* __restrict__ kprep, f16* __restrict__ vtprep) {
    int t = blockIdx.x * blockDim.x + threadIdx.x;
    if (t < 65536) {
        int b = t >> 10, r = t & 1023, u = r >> 5, kk = r & 31;
        const float* src = mem + (b * 32 + kk) * DD + u * 8;
        f16 o8[8];
#pragma unroll
        for (int e = 0; e < 8; ++e) o8[e] = (f16)src[e];
        *(f16x8*)(kprep + (size_t)t * 8) = *(f16x8*)o8;
    } else {
        int t2 = t - 65536;
        int b = t2 >> 10, r = t2 & 1023, u = r >> 8, d = r & 255;
        f16 o8[8];
#pragma unroll
        for (int e = 0; e < 8; ++e) o8[e] = (f16)mem[(b * 32 + u * 8 + e) * DD + d];
        *(f16x8*)(vtprep + (size_t)t2 * 8) = *(f16x8*)o8;
    }
}

// 256 blocks x 512 threads (8 waves x 32 q-rows), R16 pair-unrolled structure
// (best: 151us). NEW vs R16: SIMD-MATE SKEW -- after each window barrier,
// waves 4..7 (the second wave on each SIMD) sleep ~512cyc, anti-phasing the
// two waves per SIMD so one wave's LDS read-burst overlaps the other's MFMA
// burst instead of colliding (wave-level convoy breakup; block-level phasing
// was R12-null, wave-level never tested).
__launch_bounds__(512, 2)
__global__ void attn_kernel(const float* __restrict__ q,
                            const f16* __restrict__ kprep,
                            const f16* __restrict__ vtprep,
                            float* __restrict__ out) {
    __shared__ __align__(16) f16 klds[4][8192];
    __shared__ __align__(16) f16 vtlds[4][8192];

    const int tid = threadIdx.x;
    const int w = __builtin_amdgcn_readfirstlane(tid >> 6);  // 0..7
    const int lane = tid & 63;
    const int h = lane >> 5;
    const int l31 = lane & 31;
    const int q0 = blockIdx.x * 256 + w * 32;

    // Q B-frags: qf[s] lane(h,l31) elem j = Q[q0+l31][16s+8h+j]  (col=q=l31)
    f16x8 qf[16];
#pragma unroll
    for (int s = 0; s < 16; ++s) {
        const float* src = q + (size_t)(q0 + l31) * DD + s * 16 + h * 8;
        float4 a = *(const float4*)src;
        float4 b2 = *(const float4*)(src + 4);
        f16 t8[8] = {(f16)a.x, (f16)a.y, (f16)a.z, (f16)a.w,
                     (f16)b2.x, (f16)b2.y, (f16)b2.z, (f16)b2.w};
        qf[s] = *(f16x8*)t8;
    }

    f32x16 o[8];
#pragma unroll
    for (int dt = 0; dt < 8; ++dt) o[dt] = (f32x16)(0.f);
    float lpart = 0.f, mrun = -1e30f;
    f16x8 pa0 = (f16x8)(f16)0.f, pa1 = (f16x8)(f16)0.f;  // P frags of prev tile

#define STAGE_K(t_)                                                       \
    do {                                                                  \
        const f16* s_ = kprep + (size_t)(t_)*8192;                        \
        _Pragma("unroll")                                                 \
        for (int i_ = 0; i_ < 2; ++i_)                                    \
            gload_lds16(s_ + i_ * 4096 + w * 512 + lane * 8,              \
                        &klds[(t_) & 3][i_ * 4096 + w * 512]);            \
    } while (0)
#define STAGE_VT(t_)                                                      \
    do {                                                                  \
        const f16* s_ = vtprep + (size_t)(t_)*8192;                       \
        _Pragma("unroll")                                                 \
        for (int i_ = 0; i_ < 2; ++i_)                                    \
            gload_lds16(s_ + i_ * 4096 + w * 512 + lane * 8,              \
                        &vtlds[(t_) & 3][i_ * 4096 + w * 512]);           \
    } while (0)

// QK: s_ = K(t_) Q^T, 16 chained MFMAs (C: col=q=l31, row=k=(r&3)+8(r>>2)+4h)
#define QK(t_, s_)                                                            \
    do {                                                                      \
        const f16* kb_ = &klds[(t_) & 3][0];                                  \
        _Pragma("unroll")                                                     \
        for (int st_ = 0; st_ < 16; ++st_) {                                  \
            f16x8 ak_ = *(const f16x8*)(kb_ + ((2 * st_ + h) * 32 + l31) * 8);\
            s_ = mfma32(ak_, qf[st_], s_);                                    \
        }                                                                     \
    } while (0)

// PV: o += P(prev) V(t_), pa0/pa1 in regs, V from vtlds ring
#define PV(t_)                                                                 \
    do {                                                                       \
        const f16* vb_ = &vtlds[(t_) & 3][0];                                  \
        _Pragma("unroll")                                                      \
        for (int dt_ = 0; dt_ < 8; ++dt_) {                                    \
            f16x8 v0_ = *(const f16x8*)(vb_ + ((0 + h) * 256 + dt_ * 32 + l31) * 8); \
            f16x8 v1_ = *(const f16x8*)(vb_ + ((2 + h) * 256 + dt_ * 32 + l31) * 8); \
            o[dt_] = mfma32(pa0, v0_, o[dt_]);                                 \
            o[dt_] = mfma32(pa1, v1_, o[dt_]);                                 \
        }                                                                      \
    } while (0)

// softmax (base-2, defer-max) + in-register P pack -> pa0/pa1
#define SOFTMAX_PACK(s_)                                                       \
    do {                                                                       \
        float sm_ = s_[0];                                                     \
        _Pragma("unroll") for (int r_ = 1; r_ < 16; ++r_)                      \
            sm_ = fmaxf(sm_, s_[r_]);                                          \
        sm_ *= LOG2E;                                                          \
        if (__any(sm_ > mrun + 8.0f)) {                                        \
            sm_ = fmaxf(sm_, __shfl_xor(sm_, 32));                             \
            const float mn_ = fmaxf(mrun, sm_);                                \
            const float fct_ = __builtin_amdgcn_exp2f(mrun - mn_);             \
            mrun = mn_;                                                        \
            lpart *= fct_;                                                     \
            float fr_[16];                                                     \
            _Pragma("unroll") for (int r_ = 0; r_ < 16; ++r_)                  \
                fr_[r_] = __shfl(fct_, (r_ & 3) + 8 * (r_ >> 2) + 4 * h, 32);  \
            _Pragma("unroll") for (int dt_ = 0; dt_ < 8; ++dt_)                \
                _Pragma("unroll") for (int r_ = 0; r_ < 16; ++r_)              \
                    o[dt_][r_] *= fr_[r_];                                     \
        }                                                                      \
        float p_[16], rs_ = 0.f;                                               \
        _Pragma("unroll") for (int r_ = 0; r_ < 16; ++r_) {                    \
            p_[r_] = __builtin_amdgcn_exp2f(                                   \
                __builtin_fmaf(s_[r_], LOG2E, -mrun));                         \
            rs_ += p_[r_];                                                     \
        }                                                                      \
        lpart += rs_;                                                          \
        unsigned c0_ = pk2(p_[0], p_[1]), c1_ = pk2(p_[2], p_[3]);             \
        unsigned c2_ = pk2(p_[4], p_[5]), c3_ = pk2(p_[6], p_[7]);             \
        unsigned c4_ = pk2(p_[8], p_[9]), c5_ = pk2(p_[10], p_[11]);           \
        unsigned c6_ = pk2(p_[12], p_[13]), c7_ = pk2(p_[14], p_[15]);         \
        plswap(c0_, c2_); plswap(c1_, c3_);                                    \
        plswap(c4_, c6_); plswap(c5_, c7_);                                    \
        u32x4 k0_ = {c0_, c1_, c2_, c3_}, k1_ = {c4_, c5_, c6_, c7_};          \
        pa0 = __builtin_bit_cast(f16x8, k0_);                                  \
        pa1 = __builtin_bit_cast(f16x8, k1_);                                  \
    } while (0)

    // Prologue: K(0), K(1), VT(0) (drained by the first in-loop barrier).
    STAGE_K(0);
    STAGE_K(1);
    STAGE_VT(0);

    // Main loop: 32 pairs; ONE barrier per pair; SIMD-mate skew after barrier.
    for (int p = 0; p < 32; ++p) {
        const int t0 = 2 * p, t1 = 2 * p + 1;
        __syncthreads();
        // Anti-phase the two waves sharing each SIMD (w and w+4): ~512 cyc,
        // about one ds_read burst, so their read/MFMA phases interleave.
        if (w & 4) __builtin_amdgcn_s_sleep(8);
        if (p < 31) { STAGE_K(t0 + 2); STAGE_K(t1 + 2); }
        STAGE_VT(t1);                 // first read: PV(t1) next pair
        if (p < 31) STAGE_VT(t1 + 1); // first read: PV(t1+1) next pair

        __builtin_amdgcn_s_setprio(1);
        f32x16 s0 = (f32x16)(0.f);
        QK(t0, s0);
        if (p) PV(t0 - 1);
        __builtin_amdgcn_s_setprio(0);
        SOFTMAX_PACK(s0);

        __builtin_amdgcn_s_setprio(1);
        f32x16 s1 = (f32x16)(0.f);
        QK(t1, s1);
        PV(t0);
        __builtin_amdgcn_s_setprio(0);
        SOFTMAX_PACK(s1);
    }

    // Epilogue: PV(63) (VT(63) staged at pair 31; barrier drains it).
    __syncthreads();
    __builtin_amdgcn_s_setprio(1);
    PV(63);
    __builtin_amdgcn_s_setprio(0);

    const float ltot = lpart + __shfl_xor(lpart, 32);
    const float inv = 1.0f / ltot;
    float invr[16];
#pragma unroll
    for (int r = 0; r < 16; ++r)
        invr[r] = __shfl(inv, (r & 3) + 8 * (r >> 2) + 4 * h, 32);
#pragma unroll
    for (int dt = 0; dt < 8; ++dt)
#pragma unroll
        for (int r = 0; r < 16; ++r) {
            const int qrow = (r & 3) + 8 * (r >> 2) + 4 * h;
            out[(size_t)(q0 + qrow) * DD + dt * 32 + l31] = o[dt][r] * invr[r];
        }
}

extern "C" void kernel_launch(void* const* d_in, const int* in_sizes, int n_in,
                              void* d_out, int out_size, void* d_ws, size_t ws_size,
                              hipStream_t stream) {
    const float* memory = (const float*)d_in[0];
    const float* query = (const float*)d_in[1];
    float* out = (float*)d_out;
    f16* kprep = (f16*)d_ws;                 // 1 MB
    f16* vtprep = kprep + (size_t)MM * DD;   // 1 MB
    prep_kernel<<<512, 256, 0, stream>>>(memory, kprep, vtprep);
    attn_kernel<<<256, 512, 0, stream>>>(query, kprep, vtprep, out);
}